// Round 2
// baseline (505.774 us; speedup 1.0000x reference)
//
#include <hip/hip_runtime.h>

#define N_NODES 50000
#define N_EDGES 800000
#define HID 128
#define SLOT (N_NODES * HID)          // 6,400,000 floats per output block
#define W_STRIDE (HID * HID)          // 16384

// ---------------- workspace layout (byte offsets, 512-aligned) ----------------
// Only small CSR arrays live in d_ws (~4 MB total); the 25.6 MB h buffer uses
// output slot0, which is free until the final copy.
#define OFF_CNT    0ul                      // 50000*4 = 200,000
#define OFF_DINV   200192ul                 // 50000*4
#define OFF_RPTR   400384ul                 // 50001*4
#define OFF_RFILL  600576ul                 // 50000*4
#define OFF_BSUM   800768ul                 // 128*4
#define OFF_BOFS   801280ul                 // 128*4
#define OFF_SRCS   801792ul                 // 800000*4 = 3,200,000
// total ≈ 4.0 MB

// ---------------- preprocessing kernels ----------------

__global__ void k_zero_cnt(int* __restrict__ cnt) {
    int i = blockIdx.x * blockDim.x + threadIdx.x;
    if (i < N_NODES) cnt[i] = 0;
}

__global__ void k_count(const int* __restrict__ ei, int* __restrict__ cnt) {
    int e = blockIdx.x * blockDim.x + threadIdx.x;
    if (e < N_EDGES) {
        int d = ei[N_EDGES + e];          // dst row of edge_index
        atomicAdd(&cnt[d], 1);
    }
}

__global__ void k_dinv(const int* __restrict__ cnt, float* __restrict__ dinv) {
    int i = blockIdx.x * blockDim.x + threadIdx.x;
    if (i < N_NODES) {
        int c = cnt[i];
        dinv[i] = (c > 0) ? rsqrtf((float)c) : 0.0f;
    }
}

// exclusive block scan over cnt (512 elems/block), pre-offset
__global__ void k_scan_block(const int* __restrict__ cnt, int* __restrict__ rptr,
                             int* __restrict__ bsum) {
    __shared__ int s[512];
    int tid = threadIdx.x;
    int gid = blockIdx.x * 512 + tid;
    int v = (gid < N_NODES) ? cnt[gid] : 0;
    s[tid] = v;
    __syncthreads();
    for (int off = 1; off < 512; off <<= 1) {
        int t = (tid >= off) ? s[tid - off] : 0;
        __syncthreads();
        s[tid] += t;
        __syncthreads();
    }
    if (gid < N_NODES) rptr[gid] = s[tid] - v;   // exclusive
    if (tid == 511) bsum[blockIdx.x] = s[511];
}

__global__ void k_scan_sums(const int* __restrict__ bsum, int* __restrict__ bofs, int nb) {
    __shared__ int s[128];
    int tid = threadIdx.x;
    int v = (tid < nb) ? bsum[tid] : 0;
    s[tid] = v;
    __syncthreads();
    for (int off = 1; off < 128; off <<= 1) {
        int t = (tid >= off) ? s[tid - off] : 0;
        __syncthreads();
        s[tid] += t;
        __syncthreads();
    }
    if (tid < nb) bofs[tid] = s[tid] - v;        // exclusive
}

__global__ void k_scan_add(int* __restrict__ rptr, int* __restrict__ rfill,
                           const int* __restrict__ bofs) {
    int gid = blockIdx.x * blockDim.x + threadIdx.x;
    if (gid < N_NODES) {
        int r = rptr[gid] + bofs[gid >> 9];      // scan block size was 512
        rptr[gid] = r;
        rfill[gid] = r;
    }
    if (gid == 0) rptr[N_NODES] = N_EDGES;
}

__global__ void k_scatter(const int* __restrict__ ei, int* __restrict__ rfill,
                          int* __restrict__ srcs) {
    int e = blockIdx.x * blockDim.x + threadIdx.x;
    if (e < N_EDGES) {
        int sv = ei[e];                   // src row of edge_index
        int d  = ei[N_EDGES + e];         // dst row
        int pos = atomicAdd(&rfill[d], 1);
        srcs[pos] = sv;
    }
}

// ---------------- dense transform: H = (X @ W) * dinv[row] ----------------
// block = 256 threads, tile = 32 rows x 128 cols, 4x4 micro-tile per thread.
__launch_bounds__(256)
__global__ void k_gemm_scale(const float* __restrict__ X, const float* __restrict__ W,
                             const float* __restrict__ dinv, float* __restrict__ H) {
    __shared__ float sW[HID * HID];   // 64 KB
    __shared__ float sX[32 * HID];    // 16 KB
    int tid = threadIdx.x;

    // stage W (whole 128x128, K-major rows) into LDS
    for (int i = tid; i < (HID * HID) / 4; i += 256)
        ((float4*)sW)[i] = ((const float4*)W)[i];

    int row0 = blockIdx.x * 32;
    // stage 32-row X tile
    for (int i = tid; i < (32 * HID) / 4; i += 256) {
        int r  = i >> 5;          // 32 float4 per row
        int c4 = i & 31;
        int row = row0 + r;
        float4 v = {0.f, 0.f, 0.f, 0.f};
        if (row < N_NODES) v = ((const float4*)X)[row * 32 + c4];
        ((float4*)sX)[i] = v;
    }
    __syncthreads();

    int tr = tid >> 5;            // 0..7  -> rows tr*4 .. tr*4+3
    int tc = tid & 31;            // 0..31 -> cols tc*4 .. tc*4+3
    int c0 = tc * 4;

    float4 acc[4];
    #pragma unroll
    for (int r = 0; r < 4; ++r) acc[r] = {0.f, 0.f, 0.f, 0.f};

    #pragma unroll 4
    for (int k0 = 0; k0 < HID; k0 += 4) {
        float4 w0 = *(const float4*)&sW[(k0 + 0) * HID + c0];
        float4 w1 = *(const float4*)&sW[(k0 + 1) * HID + c0];
        float4 w2 = *(const float4*)&sW[(k0 + 2) * HID + c0];
        float4 w3 = *(const float4*)&sW[(k0 + 3) * HID + c0];
        #pragma unroll
        for (int r = 0; r < 4; ++r) {
            float4 xv = *(const float4*)&sX[(tr * 4 + r) * HID + k0];
            acc[r].x += xv.x * w0.x + xv.y * w1.x + xv.z * w2.x + xv.w * w3.x;
            acc[r].y += xv.x * w0.y + xv.y * w1.y + xv.z * w2.y + xv.w * w3.y;
            acc[r].z += xv.x * w0.z + xv.y * w1.z + xv.z * w2.z + xv.w * w3.z;
            acc[r].w += xv.x * w0.w + xv.y * w1.w + xv.z * w2.w + xv.w * w3.w;
        }
    }

    #pragma unroll
    for (int r = 0; r < 4; ++r) {
        int row = row0 + tr * 4 + r;
        if (row < N_NODES) {
            float dv = dinv[row];
            float4 o = {acc[r].x * dv, acc[r].y * dv, acc[r].z * dv, acc[r].w * dv};
            ((float4*)H)[row * 32 + tc] = o;
        }
    }
}

// ---------------- aggregation: out[v] = dinv[v] * sum_{src in row v} H[src] + b ----
// one wave (64 lanes) per node, float2 per lane.
__global__ void k_agg(const float* __restrict__ H, const int* __restrict__ rptr,
                      const int* __restrict__ srcs, const float* __restrict__ dinv,
                      const float* __restrict__ bias, float* __restrict__ out0) {
    int wid  = (blockIdx.x * blockDim.x + threadIdx.x) >> 6;
    int lane = threadIdx.x & 63;
    if (wid >= N_NODES) return;

    int beg = rptr[wid];
    int end = rptr[wid + 1];

    float2 acc = {0.f, 0.f};
    for (int p = beg; p < end; ++p) {
        int s = srcs[p];
        float2 hv = *(const float2*)&H[s * HID + lane * 2];
        acc.x += hv.x;
        acc.y += hv.y;
    }
    float dv  = dinv[wid];
    float2 bb = *(const float2*)&bias[lane * 2];
    float2 res = {acc.x * dv + bb.x, acc.y * dv + bb.y};
    *(float2*)&out0[wid * HID + lane * 2] = res;
}

__global__ void k_copy(const float* __restrict__ src, float* __restrict__ dst, int n4) {
    int i = blockIdx.x * blockDim.x + threadIdx.x;
    if (i < n4) ((float4*)dst)[i] = ((const float4*)src)[i];
}

// ---------------- launch ----------------

extern "C" void kernel_launch(void* const* d_in, const int* in_sizes, int n_in,
                              void* d_out, int out_size, void* d_ws, size_t ws_size,
                              hipStream_t stream) {
    const float* x  = (const float*)d_in[0];
    const int*   ei = (const int*)d_in[1];     // int32 on device (harness converts)
    const float* Ws = (const float*)d_in[2];
    const float* bs = (const float*)d_in[3];
    float* out = (float*)d_out;
    char*  ws  = (char*)d_ws;

    int*   cnt   = (int*)  (ws + OFF_CNT);
    float* dinv  = (float*)(ws + OFF_DINV);
    int*   rptr  = (int*)  (ws + OFF_RPTR);
    int*   rfill = (int*)  (ws + OFF_RFILL);
    int*   bsum  = (int*)  (ws + OFF_BSUM);
    int*   bofs  = (int*)  (ws + OFF_BOFS);
    int*   srcs  = (int*)  (ws + OFF_SRCS);

    // output slots: [0]=x3(final), [1]=x0, [2]=x1, [3]=x2, [4]=x3
    float* slot0 = out;                 // doubles as the h scratch buffer
    float* slot1 = out + 1l * SLOT;
    float* slot2 = out + 2l * SLOT;
    float* slot3 = out + 3l * SLOT;
    float* slot4 = out + 4l * SLOT;
    float* h     = slot0;

    const int NB_NODE = (N_NODES + 255) / 256;   // 196
    const int NB_EDGE = (N_EDGES + 255) / 256;   // 3125
    const int NB_SCAN = (N_NODES + 511) / 512;   // 98

    // ---- preprocessing: degrees, dinv, CSR by dst ----
    k_zero_cnt  <<<NB_NODE, 256, 0, stream>>>(cnt);
    k_count     <<<NB_EDGE, 256, 0, stream>>>(ei, cnt);
    k_dinv      <<<NB_NODE, 256, 0, stream>>>(cnt, dinv);
    k_scan_block<<<NB_SCAN, 512, 0, stream>>>(cnt, rptr, bsum);
    k_scan_sums <<<1, 128, 0, stream>>>(bsum, bofs, NB_SCAN);
    k_scan_add  <<<NB_NODE, 256, 0, stream>>>(rptr, rfill, bofs);
    k_scatter   <<<NB_EDGE, 256, 0, stream>>>(ei, rfill, srcs);

    // ---- embeddings[0] = input x ----
    k_copy<<<SLOT / 4 / 256, 256, 0, stream>>>(x, slot1, SLOT / 4);

    const int NB_GEMM = (N_NODES + 31) / 32;     // 1563
    const int NB_AGG  = (N_NODES + 3) / 4;       // 12500 (4 waves/block)

    // ---- layer 1: x1 = dinv * A_sum( (x  @ W0) * dinv ) + b0 ----
    k_gemm_scale<<<NB_GEMM, 256, 0, stream>>>(x, Ws + 0 * W_STRIDE, dinv, h);
    k_agg       <<<NB_AGG, 256, 0, stream>>>(h, rptr, srcs, dinv, bs + 0 * HID, slot2);

    // ---- layer 2 ----
    k_gemm_scale<<<NB_GEMM, 256, 0, stream>>>(slot2, Ws + 1 * W_STRIDE, dinv, h);
    k_agg       <<<NB_AGG, 256, 0, stream>>>(h, rptr, srcs, dinv, bs + 1 * HID, slot3);

    // ---- layer 3: h in slot0, aggregate into slot4, then copy slot4 -> slot0 ----
    k_gemm_scale<<<NB_GEMM, 256, 0, stream>>>(slot3, Ws + 2 * W_STRIDE, dinv, h);
    k_agg       <<<NB_AGG, 256, 0, stream>>>(h, rptr, srcs, dinv, bs + 2 * HID, slot4);
    k_copy<<<SLOT / 4 / 256, 256, 0, stream>>>(slot4, slot0, SLOT / 4);
}

// Round 4
// 428.714 us; speedup vs baseline: 1.1797x; 1.1797x over previous
//
#include <hip/hip_runtime.h>

#define N_NODES 50000
#define N_EDGES 800000
#define HID 128
#define SLOT (N_NODES * HID)          // 6,400,000 floats per output block
#define W_STRIDE (HID * HID)          // 16384

// ---------------- workspace layout (byte offsets, 512-aligned) ----------------
#define OFF_CNT    0ul                      // 50000*4 = 200,000
#define OFF_DINV   200192ul                 // 50000*4
#define OFF_RPTR   400384ul                 // 50001*4
#define OFF_RFILL  600576ul                 // 50000*4
#define OFF_BSUM   800768ul                 // 128*4
#define OFF_BOFS   801280ul                 // 128*4
#define OFF_SRCS   801792ul                 // 800000*4 = 3,200,000
// total ≈ 4.0 MB

// ---------------- preprocessing kernels ----------------

__global__ void k_zero_cnt(int* __restrict__ cnt) {
    int i = blockIdx.x * blockDim.x + threadIdx.x;
    if (i < N_NODES) cnt[i] = 0;
}

__global__ void k_count(const int* __restrict__ ei, int* __restrict__ cnt) {
    int e = blockIdx.x * blockDim.x + threadIdx.x;
    if (e < N_EDGES) {
        int d = ei[N_EDGES + e];          // dst row of edge_index
        atomicAdd(&cnt[d], 1);
    }
}

__global__ void k_dinv(const int* __restrict__ cnt, float* __restrict__ dinv) {
    int i = blockIdx.x * blockDim.x + threadIdx.x;
    if (i < N_NODES) {
        int c = cnt[i];
        dinv[i] = (c > 0) ? rsqrtf((float)c) : 0.0f;
    }
}

// exclusive block scan over cnt (512 elems/block), pre-offset
__global__ void k_scan_block(const int* __restrict__ cnt, int* __restrict__ rptr,
                             int* __restrict__ bsum) {
    __shared__ int s[512];
    int tid = threadIdx.x;
    int gid = blockIdx.x * 512 + tid;
    int v = (gid < N_NODES) ? cnt[gid] : 0;
    s[tid] = v;
    __syncthreads();
    for (int off = 1; off < 512; off <<= 1) {
        int t = (tid >= off) ? s[tid - off] : 0;
        __syncthreads();
        s[tid] += t;
        __syncthreads();
    }
    if (gid < N_NODES) rptr[gid] = s[tid] - v;   // exclusive
    if (tid == 511) bsum[blockIdx.x] = s[511];
}

__global__ void k_scan_sums(const int* __restrict__ bsum, int* __restrict__ bofs, int nb) {
    __shared__ int s[128];
    int tid = threadIdx.x;
    int v = (tid < nb) ? bsum[tid] : 0;
    s[tid] = v;
    __syncthreads();
    for (int off = 1; off < 128; off <<= 1) {
        int t = (tid >= off) ? s[tid - off] : 0;
        __syncthreads();
        s[tid] += t;
        __syncthreads();
    }
    if (tid < nb) bofs[tid] = s[tid] - v;        // exclusive
}

__global__ void k_scan_add(int* __restrict__ rptr, int* __restrict__ rfill,
                           const int* __restrict__ bofs) {
    int gid = blockIdx.x * blockDim.x + threadIdx.x;
    if (gid < N_NODES) {
        int r = rptr[gid] + bofs[gid >> 9];      // scan block size was 512
        rptr[gid] = r;
        rfill[gid] = r;
    }
    if (gid == 0) rptr[N_NODES] = N_EDGES;
}

__global__ void k_scatter(const int* __restrict__ ei, int* __restrict__ rfill,
                          int* __restrict__ srcs) {
    int e = blockIdx.x * blockDim.x + threadIdx.x;
    if (e < N_EDGES) {
        int sv = ei[e];                   // src row of edge_index
        int d  = ei[N_EDGES + e];         // dst row
        int pos = atomicAdd(&rfill[d], 1);
        srcs[pos] = sv;
    }
}

// ---------------- dense transform: H = (X @ W) * dinv[row] ----------------
// 128x128 tile, 256 threads, 8x8 micro-tile. X tile in LDS (64 KB,
// XOR-swizzled so the 8 rows of a micro-tile hit distinct bank quads on the
// b128 fragment reads). W is NOT staged: every block reads the same 64 KB of
// W straight from L2 (broadcast), removing the per-block W restage that
// dominated round 1 and keeping LDS at 64 KB (2 blocks/CU).
__launch_bounds__(256, 2)
__global__ void k_gemm_scale(const float* __restrict__ X, const float* __restrict__ W,
                             const float* __restrict__ dinv, float* __restrict__ H) {
    __shared__ float sX[128 * HID];   // 64 KB
    int tid = threadIdx.x;
    int row0 = blockIdx.x * 128;

    // stage X tile: 4096 float4s, swizzled store
    const float4* X4  = (const float4*)X;
    float4*       sX4 = (float4*)sX;
    for (int j = tid; j < 4096; j += 256) {
        int r   = j >> 5;          // 0..127
        int c4  = j & 31;          // 0..31
        int row = row0 + r;
        float4 v = {0.f, 0.f, 0.f, 0.f};
        if (row < N_NODES) v = X4[row * 32 + c4];
        sX4[r * 32 + (c4 ^ ((r >> 3) & 7))] = v;
    }
    __syncthreads();

    int ty  = tid >> 4;            // 0..15 -> rows ty*8 .. ty*8+7
    int tx  = tid & 15;            // 0..15 -> cols tx*8 .. tx*8+7
    int swz = ty & 7;

    float4 acc[8][2];
    #pragma unroll
    for (int r = 0; r < 8; ++r) {
        acc[r][0] = {0.f, 0.f, 0.f, 0.f};
        acc[r][1] = {0.f, 0.f, 0.f, 0.f};
    }

    const float4* W4 = (const float4*)W;

    #pragma unroll 2
    for (int k0 = 0; k0 < HID; k0 += 4) {
        int k4 = k0 >> 2;
        float4 xv[8];
        #pragma unroll
        for (int r = 0; r < 8; ++r)
            xv[r] = sX4[(ty * 8 + r) * 32 + (k4 ^ swz)];
        float4 wv[4][2];
        #pragma unroll
        for (int kk = 0; kk < 4; ++kk) {
            wv[kk][0] = W4[(k0 + kk) * 32 + tx * 2 + 0];
            wv[kk][1] = W4[(k0 + kk) * 32 + tx * 2 + 1];
        }
        #pragma unroll
        for (int r = 0; r < 8; ++r) {
            float xk0 = xv[r].x, xk1 = xv[r].y, xk2 = xv[r].z, xk3 = xv[r].w;
            #pragma unroll
            for (int hh = 0; hh < 2; ++hh) {
                acc[r][hh].x += xk0 * wv[0][hh].x + xk1 * wv[1][hh].x + xk2 * wv[2][hh].x + xk3 * wv[3][hh].x;
                acc[r][hh].y += xk0 * wv[0][hh].y + xk1 * wv[1][hh].y + xk2 * wv[2][hh].y + xk3 * wv[3][hh].y;
                acc[r][hh].z += xk0 * wv[0][hh].z + xk1 * wv[1][hh].z + xk2 * wv[2][hh].z + xk3 * wv[3][hh].z;
                acc[r][hh].w += xk0 * wv[0][hh].w + xk1 * wv[1][hh].w + xk2 * wv[2][hh].w + xk3 * wv[3][hh].w;
            }
        }
    }

    float4* H4 = (float4*)H;
    #pragma unroll
    for (int r = 0; r < 8; ++r) {
        int row = row0 + ty * 8 + r;
        if (row < N_NODES) {
            float dv = dinv[row];
            float4 o0 = acc[r][0], o1 = acc[r][1];
            o0.x *= dv; o0.y *= dv; o0.z *= dv; o0.w *= dv;
            o1.x *= dv; o1.y *= dv; o1.z *= dv; o1.w *= dv;
            H4[row * 32 + tx * 2 + 0] = o0;
            H4[row * 32 + tx * 2 + 1] = o1;
        }
    }
}

// ---------------- aggregation: out[v] = dinv[v] * sum_{src in row v} H[src] + b ----
// one wave per node, float2 per lane; edge loop unrolled x4 with independent
// accumulators so 4 row-gathers are in flight (latency hiding).
// NOTE: out must NOT alias H (no copy-through-self; round-3 bug).
__global__ void k_agg(const float* __restrict__ H, const int* __restrict__ rptr,
                      const int* __restrict__ srcs, const float* __restrict__ dinv,
                      const float* __restrict__ bias, float* __restrict__ out0) {
    int wid  = (blockIdx.x * blockDim.x + threadIdx.x) >> 6;
    int lane = threadIdx.x & 63;
    if (wid >= N_NODES) return;

    int beg = rptr[wid];
    int end = rptr[wid + 1];

    float2 a0 = {0.f, 0.f}, a1 = {0.f, 0.f}, a2 = {0.f, 0.f}, a3 = {0.f, 0.f};
    int p  = beg;
    int n4 = beg + ((end - beg) & ~3);
    for (; p < n4; p += 4) {
        int s0 = srcs[p + 0];
        int s1 = srcs[p + 1];
        int s2 = srcs[p + 2];
        int s3 = srcs[p + 3];
        float2 h0 = *(const float2*)&H[s0 * HID + lane * 2];
        float2 h1 = *(const float2*)&H[s1 * HID + lane * 2];
        float2 h2 = *(const float2*)&H[s2 * HID + lane * 2];
        float2 h3 = *(const float2*)&H[s3 * HID + lane * 2];
        a0.x += h0.x; a0.y += h0.y;
        a1.x += h1.x; a1.y += h1.y;
        a2.x += h2.x; a2.y += h2.y;
        a3.x += h3.x; a3.y += h3.y;
    }
    for (; p < end; ++p) {
        int s = srcs[p];
        float2 hv = *(const float2*)&H[s * HID + lane * 2];
        a0.x += hv.x; a0.y += hv.y;
    }
    float dv  = dinv[wid];
    float2 bb = *(const float2*)&bias[lane * 2];
    float2 res;
    res.x = (a0.x + a1.x + a2.x + a3.x) * dv + bb.x;
    res.y = (a0.y + a1.y + a2.y + a3.y) * dv + bb.y;
    *(float2*)&out0[wid * HID + lane * 2] = res;
}

__global__ void k_copy(const float* __restrict__ src, float* __restrict__ dst, int n4) {
    int i = blockIdx.x * blockDim.x + threadIdx.x;
    if (i < n4) ((float4*)dst)[i] = ((const float4*)src)[i];
}

// ---------------- launch ----------------

extern "C" void kernel_launch(void* const* d_in, const int* in_sizes, int n_in,
                              void* d_out, int out_size, void* d_ws, size_t ws_size,
                              hipStream_t stream) {
    const float* x  = (const float*)d_in[0];
    const int*   ei = (const int*)d_in[1];
    const float* Ws = (const float*)d_in[2];
    const float* bs = (const float*)d_in[3];
    float* out = (float*)d_out;
    char*  ws  = (char*)d_ws;

    int*   cnt   = (int*)  (ws + OFF_CNT);
    float* dinv  = (float*)(ws + OFF_DINV);
    int*   rptr  = (int*)  (ws + OFF_RPTR);
    int*   rfill = (int*)  (ws + OFF_RFILL);
    int*   bsum  = (int*)  (ws + OFF_BSUM);
    int*   bofs  = (int*)  (ws + OFF_BOFS);
    int*   srcs  = (int*)  (ws + OFF_SRCS);

    // output slots: [0]=x3(final), [1]=x0, [2]=x1, [3]=x2, [4]=x3
    float* slot0 = out;                 // doubles as the h scratch buffer
    float* slot1 = out + 1l * SLOT;
    float* slot2 = out + 2l * SLOT;
    float* slot3 = out + 3l * SLOT;
    float* slot4 = out + 4l * SLOT;
    float* h     = slot0;

    const int NB_NODE = (N_NODES + 255) / 256;   // 196
    const int NB_EDGE = (N_EDGES + 255) / 256;   // 3125
    const int NB_SCAN = (N_NODES + 511) / 512;   // 98

    // ---- preprocessing: degrees, dinv, CSR by dst ----
    k_zero_cnt  <<<NB_NODE, 256, 0, stream>>>(cnt);
    k_count     <<<NB_EDGE, 256, 0, stream>>>(ei, cnt);
    k_dinv      <<<NB_NODE, 256, 0, stream>>>(cnt, dinv);
    k_scan_block<<<NB_SCAN, 512, 0, stream>>>(cnt, rptr, bsum);
    k_scan_sums <<<1, 128, 0, stream>>>(bsum, bofs, NB_SCAN);
    k_scan_add  <<<NB_NODE, 256, 0, stream>>>(rptr, rfill, bofs);
    k_scatter   <<<NB_EDGE, 256, 0, stream>>>(ei, rfill, srcs);

    // ---- embeddings[0] = input x ----
    k_copy<<<SLOT / 4 / 256, 256, 0, stream>>>(x, slot1, SLOT / 4);

    const int NB_GEMM = (N_NODES + 127) / 128;   // 391
    const int NB_AGG  = (N_NODES + 3) / 4;       // 12500 (4 waves/block)

    // ---- layer 1 ----
    k_gemm_scale<<<NB_GEMM, 256, 0, stream>>>(x, Ws + 0 * W_STRIDE, dinv, h);
    k_agg       <<<NB_AGG, 256, 0, stream>>>(h, rptr, srcs, dinv, bs + 0 * HID, slot2);

    // ---- layer 2 ----
    k_gemm_scale<<<NB_GEMM, 256, 0, stream>>>(slot2, Ws + 1 * W_STRIDE, dinv, h);
    k_agg       <<<NB_AGG, 256, 0, stream>>>(h, rptr, srcs, dinv, bs + 1 * HID, slot3);

    // ---- layer 3: h in slot0, agg -> slot4, then copy slot4 -> slot0 (final) ----
    k_gemm_scale<<<NB_GEMM, 256, 0, stream>>>(slot3, Ws + 2 * W_STRIDE, dinv, h);
    k_agg       <<<NB_AGG, 256, 0, stream>>>(h, rptr, srcs, dinv, bs + 2 * HID, slot4);
    k_copy<<<SLOT / 4 / 256, 256, 0, stream>>>(slot4, slot0, SLOT / 4);
}

// Round 5
// 415.828 us; speedup vs baseline: 1.2163x; 1.0310x over previous
//
#include <hip/hip_runtime.h>

#define N_NODES 50000
#define N_EDGES 800000
#define HID 128
#define SLOT (N_NODES * HID)          // 6,400,000 floats per output block
#define W_STRIDE (HID * HID)          // 16384

// ---------------- workspace layout (byte offsets, 512-aligned) ----------------
#define OFF_CNT    0ul                      // 50000*4 = 200,000
#define OFF_DINV   200192ul                 // 50000*4
#define OFF_RPTR   400384ul                 // 50001*4
#define OFF_RFILL  600576ul                 // 50000*4
#define OFF_BSUM   800768ul                 // 128*4
#define OFF_BOFS   801280ul                 // 128*4
#define OFF_SRCS   801792ul                 // 800000*4 = 3,200,000
#define OFF_H_WS   4001792ul                // 50000*128*4 = 25,600,000 (optional)
// base ≈ 4.0 MB; with h ≈ 29.6 MB (used only if ws_size permits)

// ---------------- preprocessing kernels ----------------

__global__ void k_zero_cnt(int* __restrict__ cnt) {
    int i = blockIdx.x * blockDim.x + threadIdx.x;
    if (i < N_NODES) cnt[i] = 0;
}

__global__ void k_count(const int* __restrict__ ei, int* __restrict__ cnt) {
    int e = blockIdx.x * blockDim.x + threadIdx.x;
    if (e < N_EDGES) {
        int d = ei[N_EDGES + e];          // dst row of edge_index
        atomicAdd(&cnt[d], 1);
    }
}

__global__ void k_dinv(const int* __restrict__ cnt, float* __restrict__ dinv) {
    int i = blockIdx.x * blockDim.x + threadIdx.x;
    if (i < N_NODES) {
        int c = cnt[i];
        dinv[i] = (c > 0) ? rsqrtf((float)c) : 0.0f;
    }
}

// exclusive block scan over cnt (512 elems/block), pre-offset
__global__ void k_scan_block(const int* __restrict__ cnt, int* __restrict__ rptr,
                             int* __restrict__ bsum) {
    __shared__ int s[512];
    int tid = threadIdx.x;
    int gid = blockIdx.x * 512 + tid;
    int v = (gid < N_NODES) ? cnt[gid] : 0;
    s[tid] = v;
    __syncthreads();
    for (int off = 1; off < 512; off <<= 1) {
        int t = (tid >= off) ? s[tid - off] : 0;
        __syncthreads();
        s[tid] += t;
        __syncthreads();
    }
    if (gid < N_NODES) rptr[gid] = s[tid] - v;   // exclusive
    if (tid == 511) bsum[blockIdx.x] = s[511];
}

__global__ void k_scan_sums(const int* __restrict__ bsum, int* __restrict__ bofs, int nb) {
    __shared__ int s[128];
    int tid = threadIdx.x;
    int v = (tid < nb) ? bsum[tid] : 0;
    s[tid] = v;
    __syncthreads();
    for (int off = 1; off < 128; off <<= 1) {
        int t = (tid >= off) ? s[tid - off] : 0;
        __syncthreads();
        s[tid] += t;
        __syncthreads();
    }
    if (tid < nb) bofs[tid] = s[tid] - v;        // exclusive
}

__global__ void k_scan_add(int* __restrict__ rptr, int* __restrict__ rfill,
                           const int* __restrict__ bofs) {
    int gid = blockIdx.x * blockDim.x + threadIdx.x;
    if (gid < N_NODES) {
        int r = rptr[gid] + bofs[gid >> 9];      // scan block size was 512
        rptr[gid] = r;
        rfill[gid] = r;
    }
    if (gid == 0) rptr[N_NODES] = N_EDGES;
}

__global__ void k_scatter(const int* __restrict__ ei, int* __restrict__ rfill,
                          int* __restrict__ srcs) {
    int e = blockIdx.x * blockDim.x + threadIdx.x;
    if (e < N_EDGES) {
        int sv = ei[e];                   // src row of edge_index
        int d  = ei[N_EDGES + e];         // dst row
        int pos = atomicAdd(&rfill[d], 1);
        srcs[pos] = sv;
    }
}

// ---------------- dense transform: H = (X @ W) * dinv[row] ----------------
// 64x128 tile, 256 threads (4 waves), 4x8 micro-tile. X tile in LDS (32 KB,
// XOR-swizzled). W read directly from L2 (broadcast; 64 KB fits every XCD L2).
// 4 blocks/CU -> 4 waves/SIMD to hide the ~200cy L2 W-load latency that the
// previous 2-wave/SIMD version could not.
__launch_bounds__(256, 4)
__global__ void k_gemm_scale(const float* __restrict__ X, const float* __restrict__ W,
                             const float* __restrict__ dinv, float* __restrict__ H) {
    __shared__ float sX[64 * HID];    // 32 KB
    int tid = threadIdx.x;
    int row0 = blockIdx.x * 64;

    const float4* X4  = (const float4*)X;
    float4*       sX4 = (float4*)sX;
    for (int j = tid; j < 2048; j += 256) {
        int r   = j >> 5;          // 0..63
        int c4  = j & 31;          // 0..31
        int row = row0 + r;
        float4 v = {0.f, 0.f, 0.f, 0.f};
        if (row < N_NODES) v = X4[row * 32 + c4];
        sX4[r * 32 + (c4 ^ ((r >> 3) & 7))] = v;
    }
    __syncthreads();

    int ty  = tid >> 4;            // 0..15 -> rows ty*4 .. ty*4+3
    int tx  = tid & 15;            // 0..15 -> cols tx*8 .. tx*8+7
    int swz = (ty >> 1) & 7;       // == ((ty*4)>>3)&7, same for r=0..3

    float4 acc[4][2];
    #pragma unroll
    for (int r = 0; r < 4; ++r) {
        acc[r][0] = {0.f, 0.f, 0.f, 0.f};
        acc[r][1] = {0.f, 0.f, 0.f, 0.f};
    }

    const float4* W4 = (const float4*)W;

    #pragma unroll 2
    for (int k0 = 0; k0 < HID; k0 += 4) {
        int k4 = k0 >> 2;
        float4 wv[4][2];
        #pragma unroll
        for (int kk = 0; kk < 4; ++kk) {
            wv[kk][0] = W4[(k0 + kk) * 32 + tx * 2 + 0];
            wv[kk][1] = W4[(k0 + kk) * 32 + tx * 2 + 1];
        }
        float4 xv[4];
        #pragma unroll
        for (int r = 0; r < 4; ++r)
            xv[r] = sX4[(ty * 4 + r) * 32 + (k4 ^ swz)];
        #pragma unroll
        for (int r = 0; r < 4; ++r) {
            float xk0 = xv[r].x, xk1 = xv[r].y, xk2 = xv[r].z, xk3 = xv[r].w;
            #pragma unroll
            for (int hh = 0; hh < 2; ++hh) {
                acc[r][hh].x += xk0 * wv[0][hh].x + xk1 * wv[1][hh].x + xk2 * wv[2][hh].x + xk3 * wv[3][hh].x;
                acc[r][hh].y += xk0 * wv[0][hh].y + xk1 * wv[1][hh].y + xk2 * wv[2][hh].y + xk3 * wv[3][hh].y;
                acc[r][hh].z += xk0 * wv[0][hh].z + xk1 * wv[1][hh].z + xk2 * wv[2][hh].z + xk3 * wv[3][hh].z;
                acc[r][hh].w += xk0 * wv[0][hh].w + xk1 * wv[1][hh].w + xk2 * wv[2][hh].w + xk3 * wv[3][hh].w;
            }
        }
    }

    float4* H4 = (float4*)H;
    #pragma unroll
    for (int r = 0; r < 4; ++r) {
        int row = row0 + ty * 4 + r;
        if (row < N_NODES) {
            float dv = dinv[row];
            float4 o0 = acc[r][0], o1 = acc[r][1];
            o0.x *= dv; o0.y *= dv; o0.z *= dv; o0.w *= dv;
            o1.x *= dv; o1.y *= dv; o1.z *= dv; o1.w *= dv;
            H4[row * 32 + tx * 2 + 0] = o0;
            H4[row * 32 + tx * 2 + 1] = o1;
        }
    }
}

// ---------------- aggregation: out[v] = dinv[v] * sum_{src in row v} H[src] + b ----
// One wave per node. float4 per lane; lanes 0-31 (half 0) and 32-63 (half 1)
// each own 4 accumulators and process 4 edges per main-loop step -> 8 rows
// (4 KB) in flight per wave. Halves combined via __shfl_xor(.,32).
// NOTE: out0/out1 must NOT alias H.
__global__ void k_agg(const float* __restrict__ H, const int* __restrict__ rptr,
                      const int* __restrict__ srcs, const float* __restrict__ dinv,
                      const float* __restrict__ bias, float* __restrict__ out0,
                      float* __restrict__ out1) {
    int wid  = (blockIdx.x * blockDim.x + threadIdx.x) >> 6;
    int lane = threadIdx.x & 63;
    if (wid >= N_NODES) return;
    int half = lane >> 5;          // 0 or 1
    int l32  = lane & 31;          // float4 column index

    int beg = rptr[wid];
    int end = rptr[wid + 1];
    int deg = end - beg;

    const float4* H4 = (const float4*)H;

    float4 a0 = {0.f,0.f,0.f,0.f}, a1 = {0.f,0.f,0.f,0.f};
    float4 a2 = {0.f,0.f,0.f,0.f}, a3 = {0.f,0.f,0.f,0.f};

    int p = beg;
    int n8 = beg + (deg & ~7);
    for (; p < n8; p += 8) {
        int base = p + half * 4;
        int s0 = srcs[base + 0];
        int s1 = srcs[base + 1];
        int s2 = srcs[base + 2];
        int s3 = srcs[base + 3];
        float4 h0 = H4[s0 * 32 + l32];
        float4 h1 = H4[s1 * 32 + l32];
        float4 h2 = H4[s2 * 32 + l32];
        float4 h3 = H4[s3 * 32 + l32];
        a0.x += h0.x; a0.y += h0.y; a0.z += h0.z; a0.w += h0.w;
        a1.x += h1.x; a1.y += h1.y; a1.z += h1.z; a1.w += h1.w;
        a2.x += h2.x; a2.y += h2.y; a2.z += h2.z; a2.w += h2.w;
        a3.x += h3.x; a3.y += h3.y; a3.z += h3.z; a3.w += h3.w;
    }
    int rem   = deg & 7;
    int pairs = rem >> 1;
    for (int i = 0; i < pairs; ++i) {
        int e = p + 2 * i + half;
        float4 hv = H4[srcs[e] * 32 + l32];
        if (i == 0)      { a0.x += hv.x; a0.y += hv.y; a0.z += hv.z; a0.w += hv.w; }
        else if (i == 1) { a1.x += hv.x; a1.y += hv.y; a1.z += hv.z; a1.w += hv.w; }
        else             { a2.x += hv.x; a2.y += hv.y; a2.z += hv.z; a2.w += hv.w; }
    }
    if (rem & 1) {
        float4 hv = H4[srcs[end - 1] * 32 + l32];
        if (half == 0) { a3.x += hv.x; a3.y += hv.y; a3.z += hv.z; a3.w += hv.w; }
    }

    float4 s;
    s.x = a0.x + a1.x + a2.x + a3.x;
    s.y = a0.y + a1.y + a2.y + a3.y;
    s.z = a0.z + a1.z + a2.z + a3.z;
    s.w = a0.w + a1.w + a2.w + a3.w;
    s.x += __shfl_xor(s.x, 32);
    s.y += __shfl_xor(s.y, 32);
    s.z += __shfl_xor(s.z, 32);
    s.w += __shfl_xor(s.w, 32);

    if (half == 0) {
        float dv  = dinv[wid];
        float4 bb = ((const float4*)bias)[l32];
        float4 res;
        res.x = s.x * dv + bb.x;
        res.y = s.y * dv + bb.y;
        res.z = s.z * dv + bb.z;
        res.w = s.w * dv + bb.w;
        ((float4*)out0)[wid * 32 + l32] = res;
        if (out1) ((float4*)out1)[wid * 32 + l32] = res;
    }
}

__global__ void k_copy(const float* __restrict__ src, float* __restrict__ dst, int n4) {
    int i = blockIdx.x * blockDim.x + threadIdx.x;
    if (i < n4) ((float4*)dst)[i] = ((const float4*)src)[i];
}

// ---------------- launch ----------------

extern "C" void kernel_launch(void* const* d_in, const int* in_sizes, int n_in,
                              void* d_out, int out_size, void* d_ws, size_t ws_size,
                              hipStream_t stream) {
    const float* x  = (const float*)d_in[0];
    const int*   ei = (const int*)d_in[1];
    const float* Ws = (const float*)d_in[2];
    const float* bs = (const float*)d_in[3];
    float* out = (float*)d_out;
    char*  ws  = (char*)d_ws;

    int*   cnt   = (int*)  (ws + OFF_CNT);
    float* dinv  = (float*)(ws + OFF_DINV);
    int*   rptr  = (int*)  (ws + OFF_RPTR);
    int*   rfill = (int*)  (ws + OFF_RFILL);
    int*   bsum  = (int*)  (ws + OFF_BSUM);
    int*   bofs  = (int*)  (ws + OFF_BOFS);
    int*   srcs  = (int*)  (ws + OFF_SRCS);

    // output slots: [0]=x3(final), [1]=x0, [2]=x1, [3]=x2, [4]=x3
    float* slot0 = out;
    float* slot1 = out + 1l * SLOT;
    float* slot2 = out + 2l * SLOT;
    float* slot3 = out + 3l * SLOT;
    float* slot4 = out + 4l * SLOT;

    // h scratch: in d_ws if it fits (no aliasing; layer-3 dual-write),
    // else reuse slot0 and restore it with a final copy (round-4 path).
    bool   h_in_ws = ws_size >= (size_t)(OFF_H_WS + (size_t)SLOT * 4);
    float* h = h_in_ws ? (float*)(ws + OFF_H_WS) : slot0;

    const int NB_NODE = (N_NODES + 255) / 256;   // 196
    const int NB_EDGE = (N_EDGES + 255) / 256;   // 3125
    const int NB_SCAN = (N_NODES + 511) / 512;   // 98

    // ---- preprocessing: degrees, dinv, CSR by dst ----
    k_zero_cnt  <<<NB_NODE, 256, 0, stream>>>(cnt);
    k_count     <<<NB_EDGE, 256, 0, stream>>>(ei, cnt);
    k_dinv      <<<NB_NODE, 256, 0, stream>>>(cnt, dinv);
    k_scan_block<<<NB_SCAN, 512, 0, stream>>>(cnt, rptr, bsum);
    k_scan_sums <<<1, 128, 0, stream>>>(bsum, bofs, NB_SCAN);
    k_scan_add  <<<NB_NODE, 256, 0, stream>>>(rptr, rfill, bofs);
    k_scatter   <<<NB_EDGE, 256, 0, stream>>>(ei, rfill, srcs);

    // ---- embeddings[0] = input x ----
    k_copy<<<SLOT / 4 / 256, 256, 0, stream>>>(x, slot1, SLOT / 4);

    const int NB_GEMM = (N_NODES + 63) / 64;     // 782
    const int NB_AGG  = (N_NODES + 3) / 4;       // 12500 (4 waves/block)

    // ---- layer 1 ----
    k_gemm_scale<<<NB_GEMM, 256, 0, stream>>>(x, Ws + 0 * W_STRIDE, dinv, h);
    k_agg       <<<NB_AGG, 256, 0, stream>>>(h, rptr, srcs, dinv, bs + 0 * HID, slot2, nullptr);

    // ---- layer 2 ----
    k_gemm_scale<<<NB_GEMM, 256, 0, stream>>>(slot2, Ws + 1 * W_STRIDE, dinv, h);
    k_agg       <<<NB_AGG, 256, 0, stream>>>(h, rptr, srcs, dinv, bs + 1 * HID, slot3, nullptr);

    // ---- layer 3 ----
    k_gemm_scale<<<NB_GEMM, 256, 0, stream>>>(slot3, Ws + 2 * W_STRIDE, dinv, h);
    if (h_in_ws) {
        // h does not alias out -> safe to dual-write final + embeddings[3]
        k_agg<<<NB_AGG, 256, 0, stream>>>(h, rptr, srcs, dinv, bs + 2 * HID, slot4, slot0);
    } else {
        k_agg<<<NB_AGG, 256, 0, stream>>>(h, rptr, srcs, dinv, bs + 2 * HID, slot4, nullptr);
        k_copy<<<SLOT / 4 / 256, 256, 0, stream>>>(slot4, slot0, SLOT / 4);
    }
}

// Round 6
// 399.899 us; speedup vs baseline: 1.2648x; 1.0398x over previous
//
#include <hip/hip_runtime.h>

#define N_NODES 50000
#define N_EDGES 800000
#define HID 128
#define SLOT (N_NODES * HID)          // 6,400,000 floats per output block
#define W_STRIDE (HID * HID)          // 16384

// ---------------- workspace layout (byte offsets, 512-aligned) ----------------
#define OFF_CNT    0ul                      // 50000*4 = 200,000
#define OFF_DINV   200192ul                 // 50000*4
#define OFF_RPTR   400384ul                 // 50001*4
#define OFF_RFILL  600576ul                 // 50000*4
#define OFF_BSUM   800768ul                 // 128*4
#define OFF_BOFS   801280ul                 // 128*4
#define OFF_SRCS   801792ul                 // 800000*4 = 3,200,000
#define OFF_H_WS   4001792ul                // 50000*128*4 = 25,600,000 (optional)

// ---------------- preprocessing kernels ----------------

__global__ void k_zero_cnt(int* __restrict__ cnt) {
    int i = blockIdx.x * blockDim.x + threadIdx.x;
    if (i < N_NODES) cnt[i] = 0;
}

__global__ void k_count(const int* __restrict__ ei, int* __restrict__ cnt) {
    int e = blockIdx.x * blockDim.x + threadIdx.x;
    if (e < N_EDGES) {
        int d = ei[N_EDGES + e];          // dst row of edge_index
        atomicAdd(&cnt[d], 1);
    }
}

// exclusive block scan over cnt (512 elems/block), pre-offset
__global__ void k_scan_block(const int* __restrict__ cnt, int* __restrict__ rptr,
                             int* __restrict__ bsum) {
    __shared__ int s[512];
    int tid = threadIdx.x;
    int gid = blockIdx.x * 512 + tid;
    int v = (gid < N_NODES) ? cnt[gid] : 0;
    s[tid] = v;
    __syncthreads();
    for (int off = 1; off < 512; off <<= 1) {
        int t = (tid >= off) ? s[tid - off] : 0;
        __syncthreads();
        s[tid] += t;
        __syncthreads();
    }
    if (gid < N_NODES) rptr[gid] = s[tid] - v;   // exclusive
    if (tid == 511) bsum[blockIdx.x] = s[511];
}

__global__ void k_scan_sums(const int* __restrict__ bsum, int* __restrict__ bofs, int nb) {
    __shared__ int s[128];
    int tid = threadIdx.x;
    int v = (tid < nb) ? bsum[tid] : 0;
    s[tid] = v;
    __syncthreads();
    for (int off = 1; off < 128; off <<= 1) {
        int t = (tid >= off) ? s[tid - off] : 0;
        __syncthreads();
        s[tid] += t;
        __syncthreads();
    }
    if (tid < nb) bofs[tid] = s[tid] - v;        // exclusive
}

// scan finalize + dinv fused (one fewer dispatch)
__global__ void k_scan_add(int* __restrict__ rptr, int* __restrict__ rfill,
                           const int* __restrict__ bofs, const int* __restrict__ cnt,
                           float* __restrict__ dinv) {
    int gid = blockIdx.x * blockDim.x + threadIdx.x;
    if (gid < N_NODES) {
        int r = rptr[gid] + bofs[gid >> 9];      // scan block size was 512
        rptr[gid] = r;
        rfill[gid] = r;
        int c = cnt[gid];
        dinv[gid] = (c > 0) ? rsqrtf((float)c) : 0.0f;
    }
    if (gid == 0) rptr[N_NODES] = N_EDGES;
}

__global__ void k_scatter(const int* __restrict__ ei, int* __restrict__ rfill,
                          int* __restrict__ srcs) {
    int e = blockIdx.x * blockDim.x + threadIdx.x;
    if (e < N_EDGES) {
        int sv = ei[e];                   // src row of edge_index
        int d  = ei[N_EDGES + e];         // dst row
        int pos = atomicAdd(&rfill[d], 1);
        srcs[pos] = sv;
    }
}

// ---------------- dense transform: H = (X @ W) * dinv[row] ----------------
// Block computes a 64-row x 64-col output tile. Grid = 782 row-tiles x 2
// col-halves. W panel (128x64, 32 KB) is staged in LDS ONCE per block and
// reused across all 32 k-steps — W L2 traffic drops 16x vs streaming W
// per k-step (round-5 bottleneck: 820 MB from L2 per GEMM dispatch).
// X tile (64x128, 32 KB) XOR-swizzled as validated in rounds 4/5.
// 64 KB LDS -> 2 blocks/CU, 2 waves/SIMD.
__launch_bounds__(256, 2)
__global__ void k_gemm_scale(const float* __restrict__ X, const float* __restrict__ W,
                             const float* __restrict__ dinv, float* __restrict__ H) {
    __shared__ float sW[HID * 64];    // 32 KB, [k][c] for cols chalf*64..+63
    __shared__ float sX[64 * HID];    // 32 KB, swizzled
    int tid   = threadIdx.x;
    int chalf = blockIdx.x & 1;
    int row0  = (blockIdx.x >> 1) * 64;

    const float4* W4  = (const float4*)W;
    float4*       sW4 = (float4*)sW;
    for (int j = tid; j < 2048; j += 256) {
        int k  = j >> 4;           // 0..127
        int c4 = j & 15;           // 0..15
        sW4[j] = W4[k * 32 + chalf * 16 + c4];
    }

    const float4* X4  = (const float4*)X;
    float4*       sX4 = (float4*)sX;
    for (int j = tid; j < 2048; j += 256) {
        int r   = j >> 5;          // 0..63
        int c4  = j & 31;          // 0..31
        int row = row0 + r;
        float4 v = {0.f, 0.f, 0.f, 0.f};
        if (row < N_NODES) v = X4[row * 32 + c4];
        sX4[r * 32 + (c4 ^ ((r >> 3) & 7))] = v;
    }
    __syncthreads();

    int ty  = tid >> 4;            // 0..15 -> rows ty*4 .. ty*4+3
    int tx  = tid & 15;            // 0..15 -> col4 index within 64-col panel
    int swz = (ty >> 1) & 7;       // rows ty*4..+3 stay in one 8-row stripe

    float4 acc[4];
    #pragma unroll
    for (int r = 0; r < 4; ++r) acc[r] = {0.f, 0.f, 0.f, 0.f};

    #pragma unroll 4
    for (int k0 = 0; k0 < HID; k0 += 4) {
        int k4 = k0 >> 2;
        float4 wv[4];
        #pragma unroll
        for (int kk = 0; kk < 4; ++kk)
            wv[kk] = sW4[(k0 + kk) * 16 + tx];
        float4 xv[4];
        #pragma unroll
        for (int r = 0; r < 4; ++r)
            xv[r] = sX4[(ty * 4 + r) * 32 + (k4 ^ swz)];
        #pragma unroll
        for (int r = 0; r < 4; ++r) {
            float xk0 = xv[r].x, xk1 = xv[r].y, xk2 = xv[r].z, xk3 = xv[r].w;
            acc[r].x += xk0 * wv[0].x + xk1 * wv[1].x + xk2 * wv[2].x + xk3 * wv[3].x;
            acc[r].y += xk0 * wv[0].y + xk1 * wv[1].y + xk2 * wv[2].y + xk3 * wv[3].y;
            acc[r].z += xk0 * wv[0].z + xk1 * wv[1].z + xk2 * wv[2].z + xk3 * wv[3].z;
            acc[r].w += xk0 * wv[0].w + xk1 * wv[1].w + xk2 * wv[2].w + xk3 * wv[3].w;
        }
    }

    float4* H4 = (float4*)H;
    #pragma unroll
    for (int r = 0; r < 4; ++r) {
        int row = row0 + ty * 4 + r;
        if (row < N_NODES) {
            float dv = dinv[row];
            float4 o = acc[r];
            o.x *= dv; o.y *= dv; o.z *= dv; o.w *= dv;
            H4[row * 32 + chalf * 16 + tx] = o;
        }
    }
}

// ---------------- aggregation: out[v] = dinv[v] * sum_{src in row v} H[src] + b ----
// One wave per node. float4 per lane; halves own 4 accumulators each ->
// 8 rows (4 KB) in flight per wave. Halves combined via __shfl_xor(.,32).
// NOTE: out0/out1 must NOT alias H.
__global__ void k_agg(const float* __restrict__ H, const int* __restrict__ rptr,
                      const int* __restrict__ srcs, const float* __restrict__ dinv,
                      const float* __restrict__ bias, float* __restrict__ out0,
                      float* __restrict__ out1) {
    int wid  = (blockIdx.x * blockDim.x + threadIdx.x) >> 6;
    int lane = threadIdx.x & 63;
    if (wid >= N_NODES) return;
    int half = lane >> 5;          // 0 or 1
    int l32  = lane & 31;          // float4 column index

    int beg = rptr[wid];
    int end = rptr[wid + 1];
    int deg = end - beg;

    const float4* H4 = (const float4*)H;

    float4 a0 = {0.f,0.f,0.f,0.f}, a1 = {0.f,0.f,0.f,0.f};
    float4 a2 = {0.f,0.f,0.f,0.f}, a3 = {0.f,0.f,0.f,0.f};

    int p = beg;
    int n8 = beg + (deg & ~7);
    for (; p < n8; p += 8) {
        int base = p + half * 4;
        int s0 = srcs[base + 0];
        int s1 = srcs[base + 1];
        int s2 = srcs[base + 2];
        int s3 = srcs[base + 3];
        float4 h0 = H4[s0 * 32 + l32];
        float4 h1 = H4[s1 * 32 + l32];
        float4 h2 = H4[s2 * 32 + l32];
        float4 h3 = H4[s3 * 32 + l32];
        a0.x += h0.x; a0.y += h0.y; a0.z += h0.z; a0.w += h0.w;
        a1.x += h1.x; a1.y += h1.y; a1.z += h1.z; a1.w += h1.w;
        a2.x += h2.x; a2.y += h2.y; a2.z += h2.z; a2.w += h2.w;
        a3.x += h3.x; a3.y += h3.y; a3.z += h3.z; a3.w += h3.w;
    }
    int rem   = deg & 7;
    int pairs = rem >> 1;
    for (int i = 0; i < pairs; ++i) {
        int e = p + 2 * i + half;
        float4 hv = H4[srcs[e] * 32 + l32];
        if (i == 0)      { a0.x += hv.x; a0.y += hv.y; a0.z += hv.z; a0.w += hv.w; }
        else if (i == 1) { a1.x += hv.x; a1.y += hv.y; a1.z += hv.z; a1.w += hv.w; }
        else             { a2.x += hv.x; a2.y += hv.y; a2.z += hv.z; a2.w += hv.w; }
    }
    if (rem & 1) {
        float4 hv = H4[srcs[end - 1] * 32 + l32];
        if (half == 0) { a3.x += hv.x; a3.y += hv.y; a3.z += hv.z; a3.w += hv.w; }
    }

    float4 s;
    s.x = a0.x + a1.x + a2.x + a3.x;
    s.y = a0.y + a1.y + a2.y + a3.y;
    s.z = a0.z + a1.z + a2.z + a3.z;
    s.w = a0.w + a1.w + a2.w + a3.w;
    s.x += __shfl_xor(s.x, 32);
    s.y += __shfl_xor(s.y, 32);
    s.z += __shfl_xor(s.z, 32);
    s.w += __shfl_xor(s.w, 32);

    if (half == 0) {
        float dv  = dinv[wid];
        float4 bb = ((const float4*)bias)[l32];
        float4 res;
        res.x = s.x * dv + bb.x;
        res.y = s.y * dv + bb.y;
        res.z = s.z * dv + bb.z;
        res.w = s.w * dv + bb.w;
        ((float4*)out0)[wid * 32 + l32] = res;
        if (out1) ((float4*)out1)[wid * 32 + l32] = res;
    }
}

__global__ void k_copy(const float* __restrict__ src, float* __restrict__ dst, int n4) {
    int i = blockIdx.x * blockDim.x + threadIdx.x;
    if (i < n4) ((float4*)dst)[i] = ((const float4*)src)[i];
}

// ---------------- launch ----------------

extern "C" void kernel_launch(void* const* d_in, const int* in_sizes, int n_in,
                              void* d_out, int out_size, void* d_ws, size_t ws_size,
                              hipStream_t stream) {
    const float* x  = (const float*)d_in[0];
    const int*   ei = (const int*)d_in[1];
    const float* Ws = (const float*)d_in[2];
    const float* bs = (const float*)d_in[3];
    float* out = (float*)d_out;
    char*  ws  = (char*)d_ws;

    int*   cnt   = (int*)  (ws + OFF_CNT);
    float* dinv  = (float*)(ws + OFF_DINV);
    int*   rptr  = (int*)  (ws + OFF_RPTR);
    int*   rfill = (int*)  (ws + OFF_RFILL);
    int*   bsum  = (int*)  (ws + OFF_BSUM);
    int*   bofs  = (int*)  (ws + OFF_BOFS);
    int*   srcs  = (int*)  (ws + OFF_SRCS);

    // output slots: [0]=x3(final), [1]=x0, [2]=x1, [3]=x2, [4]=x3
    float* slot0 = out;
    float* slot1 = out + 1l * SLOT;
    float* slot2 = out + 2l * SLOT;
    float* slot3 = out + 3l * SLOT;
    float* slot4 = out + 4l * SLOT;

    // h scratch: in d_ws if it fits (no aliasing; layer-3 dual-write),
    // else reuse slot0 and restore it with a final copy.
    bool   h_in_ws = ws_size >= (size_t)(OFF_H_WS + (size_t)SLOT * 4);
    float* h = h_in_ws ? (float*)(ws + OFF_H_WS) : slot0;

    const int NB_NODE = (N_NODES + 255) / 256;   // 196
    const int NB_EDGE = (N_EDGES + 255) / 256;   // 3125
    const int NB_SCAN = (N_NODES + 511) / 512;   // 98

    // ---- preprocessing: degrees, dinv, CSR by dst ----
    k_zero_cnt  <<<NB_NODE, 256, 0, stream>>>(cnt);
    k_count     <<<NB_EDGE, 256, 0, stream>>>(ei, cnt);
    k_scan_block<<<NB_SCAN, 512, 0, stream>>>(cnt, rptr, bsum);
    k_scan_sums <<<1, 128, 0, stream>>>(bsum, bofs, NB_SCAN);
    k_scan_add  <<<NB_NODE, 256, 0, stream>>>(rptr, rfill, bofs, cnt, dinv);
    k_scatter   <<<NB_EDGE, 256, 0, stream>>>(ei, rfill, srcs);

    // ---- embeddings[0] = input x ----
    k_copy<<<SLOT / 4 / 256, 256, 0, stream>>>(x, slot1, SLOT / 4);

    const int NB_GEMM = 2 * ((N_NODES + 63) / 64);   // 1564 (row-tile x col-half)
    const int NB_AGG  = (N_NODES + 3) / 4;           // 12500 (4 waves/block)

    // ---- layer 1 ----
    k_gemm_scale<<<NB_GEMM, 256, 0, stream>>>(x, Ws + 0 * W_STRIDE, dinv, h);
    k_agg       <<<NB_AGG, 256, 0, stream>>>(h, rptr, srcs, dinv, bs + 0 * HID, slot2, nullptr);

    // ---- layer 2 ----
    k_gemm_scale<<<NB_GEMM, 256, 0, stream>>>(slot2, Ws + 1 * W_STRIDE, dinv, h);
    k_agg       <<<NB_AGG, 256, 0, stream>>>(h, rptr, srcs, dinv, bs + 1 * HID, slot3, nullptr);

    // ---- layer 3 ----
    k_gemm_scale<<<NB_GEMM, 256, 0, stream>>>(slot3, Ws + 2 * W_STRIDE, dinv, h);
    if (h_in_ws) {
        k_agg<<<NB_AGG, 256, 0, stream>>>(h, rptr, srcs, dinv, bs + 2 * HID, slot4, slot0);
    } else {
        k_agg<<<NB_AGG, 256, 0, stream>>>(h, rptr, srcs, dinv, bs + 2 * HID, slot4, nullptr);
        k_copy<<<SLOT / 4 / 256, 256, 0, stream>>>(slot4, slot0, SLOT / 4);
    }
}